// Round 4
// baseline (441.342 us; speedup 1.0000x reference)
//
#include <hip/hip_runtime.h>
#include <hip/hip_bf16.h>
#include <stdint.h>

// Problem constants
#define S_LEN 1024
#define B_SZ  64
#define I_SZ  512
#define H_SZ  2048
#define O_SZ  512
#define BH    (B_SZ * H_SZ)      // 131072

typedef __bf16  bf16x8 __attribute__((ext_vector_type(8)));
typedef float   f32x4  __attribute__((ext_vector_type(4)));

static __device__ __forceinline__ ushort f2bf(float f) {
  union { float f; unsigned u; } v; v.f = f;
  unsigned r = v.u + 0x7FFFu + ((v.u >> 16) & 1u);   // RNE
  return (ushort)(r >> 16);
}
static __device__ __forceinline__ float bf2f(ushort u) {
  return __builtin_bit_cast(float, (unsigned)u << 16);
}

// async global->LDS, 16B per lane, wave-uniform LDS base + lane*16
#define GLOAD_LDS16(gp, lp) \
  __builtin_amdgcn_global_load_lds( \
      (__attribute__((address_space(1))) void*)(gp), \
      (__attribute__((address_space(3))) void*)(lp), 16, 0, 0)

// ---------------------------------------------------------------- converts
// X [s][b][i] fp32 -> XT [b][s][i] bf16 (transpose so the fused kernel's
// per-batch A-tiles are contiguous 1 KB rows / 1 MB streams).
__global__ __launch_bounds__(256) void convert_transpose_x_kernel(
    const float* __restrict__ X, ushort* __restrict__ XT) {
  int r = blockIdx.x * 2 + (threadIdx.x >> 7);   // row id = s*64 + b
  int t = threadIdx.x & 127;
  int s = r >> 6, b = r & 63;
  float4 v = *(const float4*)&X[(size_t)r * I_SZ + t * 4];
  ushort4 o;
  o.x = f2bf(v.x); o.y = f2bf(v.y); o.z = f2bf(v.z); o.w = f2bf(v.w);
  *(ushort4*)&XT[((size_t)b * S_LEN + s) * I_SZ + t * 4] = o;
}

__global__ __launch_bounds__(256) void convert_f32_bf16_kernel(
    const float4* __restrict__ in, ushort4* __restrict__ out, int n4) {
  int i = blockIdx.x * 256 + threadIdx.x;
  if (i >= n4) return;
  float4 v = in[i];
  ushort4 o; o.x = f2bf(v.x); o.y = f2bf(v.y); o.z = f2bf(v.z); o.w = f2bf(v.w);
  out[i] = o;
}

// ---------------------------------------------------------------- fused GEMM + scan
// Grid: 1024 blocks = (b, ht). Block computes u[s, b, ht*128 .. +128) as 8
// sequential s-tiles of 128x128 (K=512) in LDS and advances h = |u + c*h|
// between tiles. u never touches HBM. XT layout makes A-tiles contiguous.
// LDS: As(16K)+Bs(16K) overlapped by transposed Cs[128 h][132 s] bf16 (33792B).
// Scan is a pure fma chain: p = fma(c, |p|, u)  (abs folds to input modifier).
__global__ __launch_bounds__(256, 4) void fused_gemm_scan_kernel(
    const ushort* __restrict__ XT,    // [64][1024][512] bf16
    const ushort* __restrict__ Wbf,   // [2048][512] bf16
    const float* __restrict__ hh,     // [2048]
    float* __restrict__ hstate) {     // [64][2048]
  __shared__ __align__(16) ushort smem[16896];   // 33792 B
  ushort* As = smem;                  // 128 rows x 64 k
  ushort* Bs = smem + 8192;
  ushort* Cs = smem;                  // [128 h][132 s], reuses As+Bs space

  const int tid  = threadIdx.x;
  const int wave = tid >> 6;
  const int lane = tid & 63;

  const int bid = blockIdx.x;
  const int x = bid & 7;              // XCD (bid%8 heuristic)
  const int g = bid >> 3;             // 0..127
  const int b  = (x << 3) | (g & 7);  // batch 0..63 (same-b -> same XCD)
  const int ht = g >> 3;              // h-tile 0..15

  const int wm = (wave >> 1) * 64;    // s-offset within tile
  const int wn = (wave & 1) * 64;     // h-offset within tile
  const int ml = lane & 15;
  const int q  = lane >> 4;

  // staging: wave stages 32 rows of A and B; slot s of row r holds chunk (s-r)&7
  const int r0     = wave * 32;
  const int srow   = lane >> 3;
  const int schunk = ((lane & 7) - srow) & 7;
  const ushort* gA0 = XT + ((size_t)b * S_LEN + r0 + srow) * I_SZ + schunk * 8;
  const ushort* gB  = Wbf + (size_t)(ht * 128 + r0 + srow) * I_SZ + schunk * 8;
  ushort* lA = As + r0 * 64;
  ushort* lB = Bs + r0 * 64;

  int swz[2];
  swz[0] = ((q + ml) & 7) * 8;
  swz[1] = ((4 + q + ml) & 7) * 8;
  int arow[4], brow[4];
  #pragma unroll
  for (int i = 0; i < 4; ++i) {
    arow[i] = (wm + i * 16 + ml) * 64;
    brow[i] = (wn + i * 16 + ml) * 64;
  }

  float c = 0.0f, p = 0.0f;           // p: pre-abs h state
  if (tid < 128) c = hh[ht * 128 + tid];

  for (int st = 0; st < 8; ++st) {
    f32x4 acc[4][4] = {};
    const ushort* gA = gA0 + (size_t)st * 128 * I_SZ;

    for (int kt = 0; kt < I_SZ / 64; ++kt) {
      __syncthreads();   // protects Cs readers (prev scan) / As,Bs readers
      #pragma unroll
      for (int jj = 0; jj < 4; ++jj) {
        GLOAD_LDS16(gA + (size_t)(jj * 8) * I_SZ + kt * 64, lA + jj * 512);
        GLOAD_LDS16(gB + (size_t)(jj * 8) * I_SZ + kt * 64, lB + jj * 512);
      }
      __syncthreads();
      #pragma unroll
      for (int ks = 0; ks < 2; ++ks) {
        bf16x8 af[4], bfr[4];
        #pragma unroll
        for (int i = 0; i < 4; ++i) {
          af[i]  = *(const bf16x8*)&As[arow[i] + swz[ks]];
          bfr[i] = *(const bf16x8*)&Bs[brow[i] + swz[ks]];
        }
        #pragma unroll
        for (int mi = 0; mi < 4; ++mi)
          #pragma unroll
          for (int ni = 0; ni < 4; ++ni)
            acc[mi][ni] = __builtin_amdgcn_mfma_f32_16x16x32_bf16(
                af[mi], bfr[ni], acc[mi][ni], 0, 0, 0);
      }
    }

    // epilogue: acc -> transposed Cs[h][s], 4 s-consecutive bf16 per ds_write_b64
    __syncthreads();
    const int sb = wm + q * 4;
    #pragma unroll
    for (int mi = 0; mi < 4; ++mi) {
      #pragma unroll
      for (int ni = 0; ni < 4; ++ni) {
        ushort4 o;
        o.x = f2bf(acc[mi][ni][0]); o.y = f2bf(acc[mi][ni][1]);
        o.z = f2bf(acc[mi][ni][2]); o.w = f2bf(acc[mi][ni][3]);
        *(ushort4*)&Cs[(wn + ni * 16 + ml) * 132 + sb + mi * 16] = o;
      }
    }
    __syncthreads();

    // scan: 128 threads, one h-column each, contiguous b64 reads, fma-abs chain
    if (tid < 128) {
      const ushort* col = &Cs[tid * 132];
      #pragma unroll
      for (int s0 = 0; s0 < 128; s0 += 16) {
        ushort4 v0 = *(const ushort4*)&col[s0];
        ushort4 v1 = *(const ushort4*)&col[s0 + 4];
        ushort4 v2 = *(const ushort4*)&col[s0 + 8];
        ushort4 v3 = *(const ushort4*)&col[s0 + 12];
        p = fmaf(c, fabsf(p), bf2f(v0.x)); p = fmaf(c, fabsf(p), bf2f(v0.y));
        p = fmaf(c, fabsf(p), bf2f(v0.z)); p = fmaf(c, fabsf(p), bf2f(v0.w));
        p = fmaf(c, fabsf(p), bf2f(v1.x)); p = fmaf(c, fabsf(p), bf2f(v1.y));
        p = fmaf(c, fabsf(p), bf2f(v1.z)); p = fmaf(c, fabsf(p), bf2f(v1.w));
        p = fmaf(c, fabsf(p), bf2f(v2.x)); p = fmaf(c, fabsf(p), bf2f(v2.y));
        p = fmaf(c, fabsf(p), bf2f(v2.z)); p = fmaf(c, fabsf(p), bf2f(v2.w));
        p = fmaf(c, fabsf(p), bf2f(v3.x)); p = fmaf(c, fabsf(p), bf2f(v3.y));
        p = fmaf(c, fabsf(p), bf2f(v3.z)); p = fmaf(c, fabsf(p), bf2f(v3.w));
      }
    }
  }

  if (tid < 128) hstate[(size_t)b * H_SZ + ht * 128 + tid] = fabsf(p);
}

// ---------------------------------------------------------------- final Y = h @ W_ho^T + b
__global__ __launch_bounds__(256) void init_y_kernel(
    const float* __restrict__ bho, float* __restrict__ Y) {
  int idx = blockIdx.x * 256 + threadIdx.x;   // 0..32767
  Y[idx] = bho[idx & (O_SZ - 1)];
}

// grid (og=8, kc=16); block: 64 b x 64 o tile, thread 4x4 regs, k-range 128
__global__ __launch_bounds__(256) void final_tiled_kernel(
    const float* __restrict__ hstate, const float* __restrict__ Who,
    float* __restrict__ Y) {
  __shared__ float Ws[64 * 68];
  __shared__ float Hs[64 * 68];
  const int tid = threadIdx.x;
  const int og = blockIdx.x, kc = blockIdx.y;
  const int to = tid & 15, tb = tid >> 4;     // o0 = to*4, b0 = tb*4
  float acc[4][4] = {};
  #pragma unroll
  for (int ks = 0; ks < 2; ++ks) {
    const int k0 = kc * 128 + ks * 64;
    const int r = tid >> 2, cg = (tid & 3) * 16;
    #pragma unroll
    for (int i2 = 0; i2 < 4; ++i2) {
      *(float4*)&Ws[r * 68 + cg + i2 * 4] =
          *(const float4*)&Who[(size_t)(og * 64 + r) * H_SZ + k0 + cg + i2 * 4];
      *(float4*)&Hs[r * 68 + cg + i2 * 4] =
          *(const float4*)&hstate[(size_t)r * H_SZ + k0 + cg + i2 * 4];
    }
    __syncthreads();
    #pragma unroll 4
    for (int k = 0; k < 64; ++k) {
      float wv[4], hv[4];
      #pragma unroll
      for (int jj2 = 0; jj2 < 4; ++jj2) wv[jj2] = Ws[(to * 4 + jj2) * 68 + k];
      #pragma unroll
      for (int ii = 0; ii < 4; ++ii) hv[ii] = Hs[(tb * 4 + ii) * 68 + k];
      #pragma unroll
      for (int ii = 0; ii < 4; ++ii)
        #pragma unroll
        for (int jj2 = 0; jj2 < 4; ++jj2)
          acc[ii][jj2] += hv[ii] * wv[jj2];
    }
    __syncthreads();
  }
  #pragma unroll
  for (int ii = 0; ii < 4; ++ii)
    #pragma unroll
    for (int jj2 = 0; jj2 < 4; ++jj2)
      atomicAdd(&Y[(size_t)(tb * 4 + ii) * O_SZ + og * 64 + to * 4 + jj2],
                acc[ii][jj2]);
}

// ---------------------------------------------------------------- launch
extern "C" void kernel_launch(void* const* d_in, const int* in_sizes, int n_in,
                              void* d_out, int out_size, void* d_ws, size_t ws_size,
                              hipStream_t stream) {
  (void)in_sizes; (void)n_in; (void)out_size; (void)ws_size;
  const float* X   = (const float*)d_in[0];   // [1024][64][512]
  const float* Wih = (const float*)d_in[1];   // [2048][512]
  const float* hh  = (const float*)d_in[2];   // [2048]
  const float* Who = (const float*)d_in[3];   // [512][2048]
  const float* bho = (const float*)d_in[4];   // [512]
  float* Y = (float*)d_out;                   // [64][512]

  const size_t XBF = (size_t)S_LEN * B_SZ * I_SZ * 2;  // 64 MiB
  const size_t WBF = (size_t)H_SZ * I_SZ * 2;          // 2 MiB

  char* w = (char*)d_ws;
  ushort* XT     = (ushort*)w;
  ushort* Wbf    = (ushort*)(w + XBF);
  float*  hstate = (float*) (w + XBF + WBF);

  // converts (X transposed to [b][s][i])
  convert_transpose_x_kernel<<<(S_LEN * B_SZ) / 2, 256, 0, stream>>>(X, XT);
  {
    int n4w = (int)((size_t)H_SZ * I_SZ / 4);          // 262144
    convert_f32_bf16_kernel<<<n4w / 256, 256, 0, stream>>>(
        (const float4*)Wih, (ushort4*)Wbf, n4w);
  }

  // fused GEMM + scan (u stays in LDS)
  fused_gemm_scan_kernel<<<1024, 256, 0, stream>>>(XT, Wbf, hh, hstate);

  // final
  init_y_kernel<<<(B_SZ * O_SZ) / 256, 256, 0, stream>>>(bho, Y);
  final_tiled_kernel<<<dim3(O_SZ / 64, 16), 256, 0, stream>>>(hstate, Who, Y);
}

// Round 5
// 385.799 us; speedup vs baseline: 1.1440x; 1.1440x over previous
//
#include <hip/hip_runtime.h>
#include <hip/hip_bf16.h>
#include <stdint.h>

// Problem constants
#define S_LEN 1024
#define B_SZ  64
#define I_SZ  512
#define H_SZ  2048
#define O_SZ  512
#define BH    (B_SZ * H_SZ)      // 131072

typedef __bf16  bf16x8 __attribute__((ext_vector_type(8)));
typedef float   f32x4  __attribute__((ext_vector_type(4)));

static __device__ __forceinline__ ushort f2bf(float f) {
  union { float f; unsigned u; } v; v.f = f;
  unsigned r = v.u + 0x7FFFu + ((v.u >> 16) & 1u);   // RNE
  return (ushort)(r >> 16);
}
static __device__ __forceinline__ float bf2f(ushort u) {
  return __builtin_bit_cast(float, (unsigned)u << 16);
}

// async global->LDS, 16B per lane, wave-uniform LDS base + lane*16
#define GLOAD_LDS16(gp, lp) \
  __builtin_amdgcn_global_load_lds( \
      (__attribute__((address_space(1))) void*)(gp), \
      (__attribute__((address_space(3))) void*)(lp), 16, 0, 0)

// ---------------------------------------------------------------- W convert (tiny)
__global__ __launch_bounds__(256) void convert_f32_bf16_kernel(
    const float4* __restrict__ in, ushort4* __restrict__ out, int n4) {
  int i = blockIdx.x * 256 + threadIdx.x;
  if (i >= n4) return;
  float4 v = in[i];
  ushort4 o; o.x = f2bf(v.x); o.y = f2bf(v.y); o.z = f2bf(v.z); o.w = f2bf(v.w);
  out[i] = o;
}

// ---------------------------------------------------------------- fused GEMM + scan
// Grid: 1024 blocks = (b, ht). Block computes u[s, b, ht*128..+128) as 8
// sequential s-tiles of 128x128 (K=512) in LDS and advances h = |u + c*h|.
// A (= X) is read DIRECTLY as fp32 [s][b][i]: 8x float4 per thread per kt,
// register-prefetched one kt ahead (loads fly under the current kt's MFMA),
// converted to bf16 in-register, ds_write_b128 into As (row stride 72 ushort:
// staging writes and fragment reads are both 2-way per quarter-wave = free).
// B from pre-converted Wbf via global_load_lds (rotate swizzle, stride 64).
// LDS: As(18K)+Bs(16K) overlaid by Cs[128 h][132 s] bf16 for the scan.
__global__ __launch_bounds__(256, 3) void fused_gemm_scan_kernel(
    const float* __restrict__ X,      // [1024][64][512] fp32
    const ushort* __restrict__ Wbf,   // [2048][512] bf16
    const float* __restrict__ hh,     // [2048]
    float* __restrict__ hstate) {     // [64][2048]
  __shared__ __align__(16) ushort smem[17408];   // 34816 B
  ushort* As = smem;                  // [128][72]
  ushort* Bs = smem + 9216;           // [128][64], rotate-swizzled
  ushort* Cs = smem;                  // [128 h][132 s] overlay (16896 <= 17408)

  const int tid  = threadIdx.x;
  const int wave = tid >> 6;
  const int lane = tid & 63;

  const int bid = blockIdx.x;
  const int x = bid & 7;              // XCD (bid%8 heuristic)
  const int g = bid >> 3;             // 0..127
  const int b  = (x << 3) | (g & 7);  // batch 0..63 (same-b -> same XCD)
  const int ht = g >> 3;              // h-tile 0..15

  const int wm = (wave >> 1) * 64;    // s-offset within tile
  const int wn = (wave & 1) * 64;     // h-offset within tile
  const int ml = lane & 15;
  const int q  = lane >> 4;

  // ---- A staging assignment: per j=0..3, thread covers row w*32+j*8+(lane>>3),
  //      chunk lane&7 (8 bf16 = 8 fp32 = 2 float4). Global row stride 64 KB.
  const int arow0 = wave * 32 + (lane >> 3);
  const size_t offA = (size_t)arow0 * (B_SZ * I_SZ) + (size_t)b * I_SZ + (lane & 7) * 8;

  // ---- B staging (round-3 pattern): wave stages 32 rows; slot s holds chunk (s-r)&7
  const int r0     = wave * 32;
  const int srow   = lane >> 3;
  const int schunk = ((lane & 7) - srow) & 7;
  const ushort* gB = Wbf + (size_t)(ht * 128 + r0 + srow) * I_SZ + schunk * 8;
  ushort* lB = Bs + r0 * 64;

  // fragment offsets
  int aoff[2], boff[2];
  aoff[0] = q * 8;            // chunk ks*4+q, slot==chunk, stride 72
  aoff[1] = (4 + q) * 8;
  boff[0] = ((q + ml) & 7) * 8;       // rotate swizzle, stride 64
  boff[1] = ((4 + q + ml) & 7) * 8;
  int arow[4], brow[4];
  #pragma unroll
  for (int i = 0; i < 4; ++i) {
    arow[i] = (wm + i * 16 + ml) * 72;
    brow[i] = (wn + i * 16 + ml) * 64;
  }

  float c = 0.0f, p = 0.0f;           // p: pre-abs h state
  if (tid < 128) c = hh[ht * 128 + tid];

  float4 ar[8];
  // prime the A prefetch: (st=0, kt=0)
  {
    const float* gp = X + offA;
    #pragma unroll
    for (int j = 0; j < 4; ++j) {
      ar[2 * j]     = *(const float4*)(gp + (size_t)j * (8 * B_SZ * I_SZ));
      ar[2 * j + 1] = *(const float4*)(gp + (size_t)j * (8 * B_SZ * I_SZ) + 4);
    }
  }

  for (int st = 0; st < 8; ++st) {
    f32x4 acc[4][4] = {};

    for (int kt = 0; kt < I_SZ / 64; ++kt) {
      __syncthreads();   // prev frag reads / Cs scan done before restaging
      // A: convert prefetched regs -> LDS (ds_write_b128, 2-way banks)
      #pragma unroll
      for (int j = 0; j < 4; ++j) {
        union { __bf16 h[8]; uint4 v; } uvt;
        uvt.h[0] = (__bf16)ar[2 * j].x;     uvt.h[1] = (__bf16)ar[2 * j].y;
        uvt.h[2] = (__bf16)ar[2 * j].z;     uvt.h[3] = (__bf16)ar[2 * j].w;
        uvt.h[4] = (__bf16)ar[2 * j + 1].x; uvt.h[5] = (__bf16)ar[2 * j + 1].y;
        uvt.h[6] = (__bf16)ar[2 * j + 1].z; uvt.h[7] = (__bf16)ar[2 * j + 1].w;
        *(uint4*)&As[(arow0 + j * 8) * 72 + (lane & 7) * 8] = uvt.v;
      }
      // B: async global->LDS
      #pragma unroll
      for (int jj = 0; jj < 4; ++jj)
        GLOAD_LDS16(gB + (size_t)(jj * 8) * I_SZ + kt * 64, lB + jj * 512);
      // prefetch next A-tile (flies under this kt's MFMA / the st-end scan)
      {
        int nst = (kt == 7) ? st + 1 : st;
        int nkt = (kt == 7) ? 0 : kt + 1;
        if (nst < 8) {
          const float* gp = X + offA + (size_t)nst * (128 * B_SZ * I_SZ) + nkt * 64;
          #pragma unroll
          for (int j = 0; j < 4; ++j) {
            ar[2 * j]     = *(const float4*)(gp + (size_t)j * (8 * B_SZ * I_SZ));
            ar[2 * j + 1] = *(const float4*)(gp + (size_t)j * (8 * B_SZ * I_SZ) + 4);
          }
        }
      }
      __syncthreads();   // staging visible
      #pragma unroll
      for (int ks = 0; ks < 2; ++ks) {
        bf16x8 af[4], bfr[4];
        #pragma unroll
        for (int i = 0; i < 4; ++i) {
          af[i]  = *(const bf16x8*)&As[arow[i] + (ks * 4) * 8 + aoff[0] - q * 8 + q * 8];
          bfr[i] = *(const bf16x8*)&Bs[brow[i] + boff[ks]];
        }
        // (aoff arithmetic folded: chunk = ks*4+q -> offset (ks*4+q)*8)
        #pragma unroll
        for (int i = 0; i < 4; ++i)
          af[i] = *(const bf16x8*)&As[arow[i] + (ks * 4 + q) * 8];
        #pragma unroll
        for (int mi = 0; mi < 4; ++mi)
          #pragma unroll
          for (int ni = 0; ni < 4; ++ni)
            acc[mi][ni] = __builtin_amdgcn_mfma_f32_16x16x32_bf16(
                af[mi], bfr[ni], acc[mi][ni], 0, 0, 0);
      }
    }

    // epilogue: acc -> transposed Cs[h][s], ds_write_b64 (proven conflict-free)
    __syncthreads();
    const int sb = wm + q * 4;
    #pragma unroll
    for (int mi = 0; mi < 4; ++mi) {
      #pragma unroll
      for (int ni = 0; ni < 4; ++ni) {
        ushort4 o;
        o.x = f2bf(acc[mi][ni][0]); o.y = f2bf(acc[mi][ni][1]);
        o.z = f2bf(acc[mi][ni][2]); o.w = f2bf(acc[mi][ni][3]);
        *(ushort4*)&Cs[(wn + ni * 16 + ml) * 132 + sb + mi * 16] = o;
      }
    }
    __syncthreads();

    // scan: 128 threads, one h-column each; fma with |.| input modifier
    if (tid < 128) {
      const ushort* col = &Cs[tid * 132];
      #pragma unroll
      for (int s0 = 0; s0 < 128; s0 += 16) {
        ushort4 v0 = *(const ushort4*)&col[s0];
        ushort4 v1 = *(const ushort4*)&col[s0 + 4];
        ushort4 v2 = *(const ushort4*)&col[s0 + 8];
        ushort4 v3 = *(const ushort4*)&col[s0 + 12];
        p = fmaf(c, fabsf(p), bf2f(v0.x)); p = fmaf(c, fabsf(p), bf2f(v0.y));
        p = fmaf(c, fabsf(p), bf2f(v0.z)); p = fmaf(c, fabsf(p), bf2f(v0.w));
        p = fmaf(c, fabsf(p), bf2f(v1.x)); p = fmaf(c, fabsf(p), bf2f(v1.y));
        p = fmaf(c, fabsf(p), bf2f(v1.z)); p = fmaf(c, fabsf(p), bf2f(v1.w));
        p = fmaf(c, fabsf(p), bf2f(v2.x)); p = fmaf(c, fabsf(p), bf2f(v2.y));
        p = fmaf(c, fabsf(p), bf2f(v2.z)); p = fmaf(c, fabsf(p), bf2f(v2.w));
        p = fmaf(c, fabsf(p), bf2f(v3.x)); p = fmaf(c, fabsf(p), bf2f(v3.y));
        p = fmaf(c, fabsf(p), bf2f(v3.z)); p = fmaf(c, fabsf(p), bf2f(v3.w));
      }
    }
  }

  if (tid < 128) hstate[(size_t)b * H_SZ + ht * 128 + tid] = fabsf(p);
}

// ---------------------------------------------------------------- final Y = h @ W_ho^T + b
__global__ __launch_bounds__(256) void init_y_kernel(
    const float* __restrict__ bho, float* __restrict__ Y) {
  int idx = blockIdx.x * 256 + threadIdx.x;   // 0..32767
  Y[idx] = bho[idx & (O_SZ - 1)];
}

// grid (og=8, kc=16); block: 64 b x 64 o tile, thread 4x4 regs, k-range 128
__global__ __launch_bounds__(256) void final_tiled_kernel(
    const float* __restrict__ hstate, const float* __restrict__ Who,
    float* __restrict__ Y) {
  __shared__ float Ws[64 * 68];
  __shared__ float Hs[64 * 68];
  const int tid = threadIdx.x;
  const int og = blockIdx.x, kc = blockIdx.y;
  const int to = tid & 15, tb = tid >> 4;     // o0 = to*4, b0 = tb*4
  float acc[4][4] = {};
  #pragma unroll
  for (int ks = 0; ks < 2; ++ks) {
    const int k0 = kc * 128 + ks * 64;
    const int r = tid >> 2, cg = (tid & 3) * 16;
    #pragma unroll
    for (int i2 = 0; i2 < 4; ++i2) {
      *(float4*)&Ws[r * 68 + cg + i2 * 4] =
          *(const float4*)&Who[(size_t)(og * 64 + r) * H_SZ + k0 + cg + i2 * 4];
      *(float4*)&Hs[r * 68 + cg + i2 * 4] =
          *(const float4*)&hstate[(size_t)r * H_SZ + k0 + cg + i2 * 4];
    }
    __syncthreads();
    #pragma unroll 4
    for (int k = 0; k < 64; ++k) {
      float wv[4], hv[4];
      #pragma unroll
      for (int jj2 = 0; jj2 < 4; ++jj2) wv[jj2] = Ws[(to * 4 + jj2) * 68 + k];
      #pragma unroll
      for (int ii = 0; ii < 4; ++ii) hv[ii] = Hs[(tb * 4 + ii) * 68 + k];
      #pragma unroll
      for (int ii = 0; ii < 4; ++ii)
        #pragma unroll
        for (int jj2 = 0; jj2 < 4; ++jj2)
          acc[ii][jj2] += hv[ii] * wv[jj2];
    }
    __syncthreads();
  }
  #pragma unroll
  for (int ii = 0; ii < 4; ++ii)
    #pragma unroll
    for (int jj2 = 0; jj2 < 4; ++jj2)
      atomicAdd(&Y[(size_t)(tb * 4 + ii) * O_SZ + og * 64 + to * 4 + jj2],
                acc[ii][jj2]);
}

// ---------------------------------------------------------------- launch
extern "C" void kernel_launch(void* const* d_in, const int* in_sizes, int n_in,
                              void* d_out, int out_size, void* d_ws, size_t ws_size,
                              hipStream_t stream) {
  (void)in_sizes; (void)n_in; (void)out_size; (void)ws_size;
  const float* X   = (const float*)d_in[0];   // [1024][64][512]
  const float* Wih = (const float*)d_in[1];   // [2048][512]
  const float* hh  = (const float*)d_in[2];   // [2048]
  const float* Who = (const float*)d_in[3];   // [512][2048]
  const float* bho = (const float*)d_in[4];   // [512]
  float* Y = (float*)d_out;                   // [64][512]

  const size_t WBF = (size_t)H_SZ * I_SZ * 2;          // 2 MiB

  char* w = (char*)d_ws;
  ushort* Wbf    = (ushort*)w;
  float*  hstate = (float*) (w + WBF);

  // W convert (tiny)
  {
    int n4w = (int)((size_t)H_SZ * I_SZ / 4);          // 262144
    convert_f32_bf16_kernel<<<n4w / 256, 256, 0, stream>>>(
        (const float4*)Wih, (ushort4*)Wbf, n4w);
  }

  // fused GEMM + scan: X fp32 read directly, u stays in LDS
  fused_gemm_scan_kernel<<<1024, 256, 0, stream>>>(X, Wbf, hh, hstate);

  // final
  init_y_kernel<<<(B_SZ * O_SZ) / 256, 256, 0, stream>>>(bho, Y);
  final_tiled_kernel<<<dim3(O_SZ / 64, 16), 256, 0, stream>>>(hstate, Who, Y);
}